// Round 17
// baseline (115.117 us; speedup 1.0000x reference)
//
#include <hip/hip_runtime.h>

// ---------------------------------------------------------------------------
// LocalitySelfAttention: y = proj( attn(x@Wqkv^T) ) for B=8,N=2048,C=384,H=6
// All internal compute bf16 MFMA + fp32 accum. Output fp32.
// R17: k_proj gets the R16 transpose-epilogue treatment: output tile staged
// in (reused) LDS with bias folded, streamed as f32x4 stores with 256B
// lane-contiguous segments (was 32 scalar f32 stores / 64B segments).
// k_cvt2/k_qkv/k_attn identical to R16.
// ---------------------------------------------------------------------------

using f32x4 = __attribute__((ext_vector_type(4))) float;
using s16x8 = __attribute__((ext_vector_type(8))) short;
using u16x4 = __attribute__((ext_vector_type(4))) unsigned short;
using u32x2 = __attribute__((ext_vector_type(2))) unsigned int;
using u32x4 = __attribute__((ext_vector_type(4))) unsigned int;
typedef unsigned short u16;
typedef unsigned int u32;

#define MFMA16(a, b, c) __builtin_amdgcn_mfma_f32_16x16x32_bf16(a, b, c, 0, 0, 0)
#define LOG2E 1.4426950408889634f
#define SQRTC 19.595917942265423f

__device__ __forceinline__ u16 f2bf(float f) {
  u32 u = __float_as_uint(f);
  u += 0x7fffu + ((u >> 16) & 1u);   // RNE
  return (u16)(u >> 16);
}

__device__ __forceinline__ u32 cvtpk(float lo, float hi) {
  u32 r;
  asm("v_cvt_pk_bf16_f32 %0, %1, %2" : "=v"(r) : "v"(lo), "v"(hi));
  return r;
}

__device__ __forceinline__ float fexp2(float x) {  // 2^x, single v_exp_f32
  float r;
  asm("v_exp_f32 %0, %1" : "=v"(r) : "v"(x));
  return r;
}

__device__ __forceinline__ void gld16(const void* g, void* l) {
  __builtin_amdgcn_global_load_lds((const __attribute__((address_space(1))) void*)g,
                                   (__attribute__((address_space(3))) void*)l, 16, 0, 0);
}

// --------------------------- fp32 -> bf16 convert (both weights) ------------
__global__ __launch_bounds__(256) void k_cvt2(const float* __restrict__ A,
                                              u16* __restrict__ Oa,
                                              const float* __restrict__ B,
                                              u16* __restrict__ Ob) {
  const int bid = blockIdx.x;
  const float* in;
  u16* out;
  size_t i;
  if (bid < 216) { in = A; out = Oa; i = (size_t)bid * 256 + threadIdx.x; }
  else           { in = B; out = Ob; i = (size_t)(bid - 216) * 256 + threadIdx.x; }
  f32x4 v0 = *(const f32x4*)(in + i * 8);
  f32x4 v1 = *(const f32x4*)(in + i * 8 + 4);
  u32x4 o;
  o[0] = cvtpk(v0[0], v0[1]); o[1] = cvtpk(v0[2], v0[3]);
  o[2] = cvtpk(v1[0], v1[1]); o[3] = cvtpk(v1[2], v1[3]);
  *(u32x4*)(out + i * 8) = o;
}

// --------------------------- QKV GEMM (M=16384,N=1152,K=384) ----------------
// Staging LDS (32KB) is reused post-loop as a 128x128 bf16 transpose tile so
// all three outputs get coalesced u16x8 stores.
__global__ __launch_bounds__(256) void k_qkv(const float* __restrict__ X,
                                             const u16* __restrict__ W,
                                             const float* __restrict__ temp,
                                             u16* __restrict__ Qt,
                                             u16* __restrict__ Kb,
                                             u16* __restrict__ Vt) {
  __shared__ u16 smem[16384];   // [0,8192): As[2][4096]; [8192,16384): Bs[2][4096]
  const int tid = threadIdx.x, w = tid >> 6, l = tid & 63, lr = l & 15, lg = l >> 4;
  const int id = blockIdx.y * 9 + blockIdx.x;
  const int swz = (id & 7) * 144 + (id >> 3);
  const int tn = (swz % 9) * 128, tm = (swz / 9) * 128;
  const int wr = w >> 1, wc = w & 1;
  const int r0 = tid >> 2, c8 = (tid & 3) * 8;
  const int ar = tid >> 1, ac = (tid & 1) * 16;

  f32x4 acc[4][4] = {};
  f32x4 a4[4];

  auto issueA = [&](int kt) {
    const float* xp = X + (size_t)(tm + ar) * 384 + kt * 32 + ac;
    a4[0] = *(const f32x4*)(xp);
    a4[1] = *(const f32x4*)(xp + 4);
    a4[2] = *(const f32x4*)(xp + 8);
    a4[3] = *(const f32x4*)(xp + 12);
  };
  auto commitA = [&](int buf) {
    u32x4 h0, h1;
    h0[0] = cvtpk(a4[0][0], a4[0][1]); h0[1] = cvtpk(a4[0][2], a4[0][3]);
    h0[2] = cvtpk(a4[1][0], a4[1][1]); h0[3] = cvtpk(a4[1][2], a4[1][3]);
    h1[0] = cvtpk(a4[2][0], a4[2][1]); h1[1] = cvtpk(a4[2][2], a4[2][3]);
    h1[2] = cvtpk(a4[3][0], a4[3][1]); h1[3] = cvtpk(a4[3][2], a4[3][3]);
    *(u32x4*)&smem[buf * 4096 + ar * 32 + ac] = h0;
    *(u32x4*)&smem[buf * 4096 + ar * 32 + ac + 8] = h1;
  };
  auto stageB = [&](int buf, int kt) {
    const int k0 = kt * 32;
    char* db = (char*)&smem[8192 + buf * 4096] + (w << 10);
    gld16(W + (size_t)(tn + r0) * 384 + k0 + c8, db);
    gld16(W + (size_t)(tn + 64 + r0) * 384 + k0 + c8, db + 4096);
  };

  issueA(0); stageB(0, 0); commitA(0);
  for (int kt = 0; kt < 12; ++kt) {
    __syncthreads();
    if (kt < 11) { issueA(kt + 1); stageB((kt + 1) & 1, kt + 1); }
    const int buf = kt & 1;
    s16x8 af[4], bfr[4];
    for (int mi = 0; mi < 4; mi++)
      af[mi] = *(const s16x8*)&smem[buf * 4096 + (wr * 64 + mi * 16 + lr) * 32 + lg * 8];
    for (int ni = 0; ni < 4; ni++)
      bfr[ni] = *(const s16x8*)&smem[8192 + buf * 4096 + (wc * 64 + ni * 16 + lr) * 32 + lg * 8];
    for (int mi = 0; mi < 4; mi++)
      for (int ni = 0; ni < 4; ni++)
        acc[mi][ni] = MFMA16(af[mi], bfr[ni], acc[mi][ni]);
    if (kt < 11) commitA((kt + 1) & 1);
  }

  // ------------------ epilogue: LDS transpose + coalesced stores ------------
  const int which = tn / 384;                 // block-uniform (blocks don't straddle)
  const int hbase = (tn - which * 384) >> 6;  // 0, 2, or 4
  const int bidx = tm >> 11;
  const int tml = tm & 2047;

  __syncthreads();   // all waves done reading staging LDS
  char* const T = (char*)smem;

  if (which == 1) {
    // K: T[m][n] plain rows of 256B; dest Kb[bh][pos][d] rows of 128B.
    for (int mi = 0; mi < 4; mi++)
      for (int ni = 0; ni < 4; ni++) {
        const int n = wc * 64 + ni * 16 + lr;
        for (int j = 0; j < 4; j++) {
          const int m = wr * 64 + mi * 16 + lg * 4 + j;
          *(u16*)(T + ((m * 256 + n * 2) ^ ((m & 7) << 4))) = f2bf(acc[mi][ni][j]);
        }
      }
    __syncthreads();
    for (int s = 0; s < 8; ++s) {
      const int rr = s * 16 + (tid >> 4), c = tid & 15;
      s16x8 v = *(const s16x8*)(T + ((rr * 256 + c * 16) ^ ((rr & 7) << 4)));
      const int hl = c >> 3, d0 = (c & 7) * 8;
      *(s16x8*)&Kb[((size_t)(bidx * 6 + hbase + hl) * 2048 + tml + rr) * 64 + d0] = v;
    }
  } else {
    // Q/V: T[n][m] transposed rows of 256B; dest [bh][d][pos] rows (pos-contig).
    const float mult = (which == 0) ? (LOG2E / (SQRTC * temp[hbase + wc])) : 1.0f;
    for (int mi = 0; mi < 4; mi++)
      for (int ni = 0; ni < 4; ni++) {
        const int n = wc * 64 + ni * 16 + lr;
        const int m0 = wr * 64 + mi * 16 + lg * 4;
        u16x4 vv;
        vv[0] = f2bf(acc[mi][ni][0] * mult); vv[1] = f2bf(acc[mi][ni][1] * mult);
        vv[2] = f2bf(acc[mi][ni][2] * mult); vv[3] = f2bf(acc[mi][ni][3] * mult);
        *(u16x4*)(T + ((n * 256 + m0 * 2) ^ ((n & 7) << 4))) = vv;
      }
    __syncthreads();
    u16* const dst = (which == 0) ? Qt : Vt;
    for (int s = 0; s < 8; ++s) {
      const int r = s * 16 + (tid >> 4), c = tid & 15;
      s16x8 v = *(const s16x8*)(T + ((r * 256 + c * 16) ^ ((r & 7) << 4)));
      const int hl = r >> 6, d = r & 63;
      *(s16x8*)&dst[((size_t)(bidx * 6 + hbase + hl) * 64 + d) * 2048 + tml + c * 8] = v;
    }
  }
}

// --------------------------- Flash attention (in-register P) ----------------
// grid = 48 bh * 16 q-tiles (XCD-swizzled). Block: 4 waves x 32 q-rows.
// K/V: reg-staged dbuf XOR-swizzled LDS. P packed in registers (sigma order);
// V read in sigma order via paired ds_read_b64. Row sums via ones-MFMA.
#define LDSOFF(row, c16) (((row) * 128 + (c16) * 16) ^ (((row) & 7) << 4))

__global__ __launch_bounds__(256, 3) void k_attn(const u16* __restrict__ Qt,
                                                 const u16* __restrict__ Kb,
                                                 const u16* __restrict__ Vt,
                                                 u16* __restrict__ AO) {
  __shared__ u16 Ks[2][64 * 64];
  __shared__ u16 Vs[2][64 * 64];
  const int tid = threadIdx.x, w = tid >> 6, l = tid & 63, lr = l & 15, lg = l >> 4;
  const int orig = blockIdx.x;
  const int rm = (orig & 7) * 96 + (orig >> 3);
  const int qt = rm & 15, bh = rm >> 4;
  const int h = bh % 6, b = bh / 6;
  const size_t base = (size_t)bh << 17;
  const int q0 = qt * 128 + w * 32;
  const int maskKt = q0 >> 6;
  const int qo = q0 & 63;

  s16x8 qf[2][2];
  for (int mi = 0; mi < 2; mi++)
    for (int ks = 0; ks < 2; ks++) {
      const u16* qp = Qt + base + (size_t)(ks * 32 + lg * 8) * 2048 + q0 + mi * 16 + lr;
      s16x8 q;
      for (int e = 0; e < 8; ++e) q[e] = (short)qp[(size_t)e * 2048];
      qf[mi][ks] = q;
    }

  s16x8 ones;
  for (int e = 0; e < 8; ++e) ones[e] = (short)0x3F80;  // bf16 1.0

  f32x4 o0[4] = {}, o1[4] = {};
  f32x4 os0 = {}, os1 = {};

  const int r0 = tid >> 3, c0 = tid & 7;
  const int c8 = c0 * 8;
  const int wo0 = LDSOFF(r0, c0), wo1 = LDSOFF(r0 + 32, c0);

  s16x8 ka0, ka1, va0, va1;
  auto issue = [&](int kt) {
    const u16* kp = Kb + base + (size_t)(kt * 64 + r0) * 64 + c8;
    ka0 = *(const s16x8*)kp;
    ka1 = *(const s16x8*)(kp + 32 * 64);
    const u16* vp = Vt + base + (size_t)r0 * 2048 + kt * 64 + c8;
    va0 = *(const s16x8*)vp;
    va1 = *(const s16x8*)(vp + 32 * 2048);
  };
  auto commit = [&](int buf) {
    char* kd = (char*)&Ks[buf][0];
    char* vd = (char*)&Vs[buf][0];
    *(s16x8*)(kd + wo0) = ka0; *(s16x8*)(kd + wo1) = ka1;
    *(s16x8*)(vd + wo0) = va0; *(s16x8*)(vd + wo1) = va1;
  };

  issue(0); commit(0);
  __syncthreads();

  const int lrs = (lr & 7) << 4;
  const int x0 = (lg * 16) ^ lrs;
  const int x1 = (64 + lg * 16) ^ lrs;
  const int vo0 = (lg * 8) ^ lrs;
  const int vo1 = (32 + lg * 8) ^ lrs;
  const int vo2 = (64 + lg * 8) ^ lrs;
  const int vo3 = (96 + lg * 8) ^ lrs;

  for (int kt = 0; kt < 32; ++kt) {
    const int cur = kt & 1;
    if (kt < 31) issue(kt + 1);

    f32x4 st0[4] = {}, st1[4] = {};
    const char* kbp = (const char*)&Ks[cur][0];
    __builtin_amdgcn_s_setprio(1);
    for (int ni = 0; ni < 4; ++ni) {
      const int rb = (ni * 16 + lr) * 128;
      const s16x8 kf0 = *(const s16x8*)(kbp + (rb + x0));
      const s16x8 kf1 = *(const s16x8*)(kbp + (rb + x1));
      st0[ni] = MFMA16(kf0, qf[0][0], st0[ni]);
      st0[ni] = MFMA16(kf1, qf[0][1], st0[ni]);
      st1[ni] = MFMA16(kf0, qf[1][0], st1[ni]);
      st1[ni] = MFMA16(kf1, qf[1][1], st1[ni]);
    }
    __builtin_amdgcn_s_setprio(0);

    if (kt == maskKt) {
      for (int ni = 0; ni < 4; ++ni)
        for (int j = 0; j < 4; ++j) {
          const int kvl = ni * 16 + lg * 4 + j;
          if (kvl == qo + lr)      st0[ni][j] = -1e30f;
          if (kvl == qo + 16 + lr) st1[ni][j] = -1e30f;
        }
    }

    const char* vbp = (const char*)&Vs[cur][0];
    s16x8 vfr[2][4];
    for (int dj = 0; dj < 4; ++dj) {
      const int rb = (dj * 16 + lr) * 128;
      u32x2 a = *(const u32x2*)(vbp + rb + vo0);
      u32x2 bq = *(const u32x2*)(vbp + rb + vo1);
      u32x2 c = *(const u32x2*)(vbp + rb + vo2);
      u32x2 d = *(const u32x2*)(vbp + rb + vo3);
      u32x4 t0; t0[0] = a[0]; t0[1] = a[1]; t0[2] = bq[0]; t0[3] = bq[1];
      u32x4 t1; t1[0] = c[0]; t1[1] = c[1]; t1[2] = d[0]; t1[3] = d[1];
      vfr[0][dj] = __builtin_bit_cast(s16x8, t0);
      vfr[1][dj] = __builtin_bit_cast(s16x8, t1);
    }

    {
      u32 pk[8];
      for (int ni = 0; ni < 4; ++ni) {
        pk[ni * 2]     = cvtpk(fexp2(st0[ni][0]), fexp2(st0[ni][1]));
        pk[ni * 2 + 1] = cvtpk(fexp2(st0[ni][2]), fexp2(st0[ni][3]));
      }
      u32x4 a0; a0[0] = pk[0]; a0[1] = pk[1]; a0[2] = pk[2]; a0[3] = pk[3];
      u32x4 a1; a1[0] = pk[4]; a1[1] = pk[5]; a1[2] = pk[6]; a1[3] = pk[7];
      const s16x8 pa0 = __builtin_bit_cast(s16x8, a0);
      const s16x8 pa1 = __builtin_bit_cast(s16x8, a1);
      __builtin_amdgcn_s_setprio(1);
      for (int dj = 0; dj < 4; ++dj) o0[dj] = MFMA16(pa0, vfr[0][dj], o0[dj]);
      os0 = MFMA16(pa0, ones, os0);
      for (int dj = 0; dj < 4; ++dj) o0[dj] = MFMA16(pa1, vfr[1][dj], o0[dj]);
      os0 = MFMA16(pa1, ones, os0);
      __builtin_amdgcn_s_setprio(0);
    }
    {
      u32 pk[8];
      for (int ni = 0; ni < 4; ++ni) {
        pk[ni * 2]     = cvtpk(fexp2(st1[ni][0]), fexp2(st1[ni][1]));
        pk[ni * 2 + 1] = cvtpk(fexp2(st1[ni][2]), fexp2(st1[ni][3]));
      }
      u32x4 a0; a0[0] = pk[0]; a0[1] = pk[1]; a0[2] = pk[2]; a0[3] = pk[3];
      u32x4 a1; a1[0] = pk[4]; a1[1] = pk[5]; a1[2] = pk[6]; a1[3] = pk[7];
      const s16x8 pa0 = __builtin_bit_cast(s16x8, a0);
      const s16x8 pa1 = __builtin_bit_cast(s16x8, a1);
      __builtin_amdgcn_s_setprio(1);
      for (int dj = 0; dj < 4; ++dj) o1[dj] = MFMA16(pa0, vfr[0][dj], o1[dj]);
      os1 = MFMA16(pa0, ones, os1);
      for (int dj = 0; dj < 4; ++dj) o1[dj] = MFMA16(pa1, vfr[1][dj], o1[dj]);
      os1 = MFMA16(pa1, ones, os1);
      __builtin_amdgcn_s_setprio(0);
    }

    if (kt < 31) commit(cur ^ 1);
    __syncthreads();
  }

  f32x4 rv0, rv1;
  for (int j = 0; j < 4; ++j) { rv0[j] = 1.0f / os0[j]; rv1[j] = 1.0f / os1[j]; }
  const size_t aobase = (size_t)b * 2048 * 384 + (size_t)h * 64;
  for (int j = 0; j < 4; ++j) {
    const int pos0 = q0 + lg * 4 + j;
    const int pos1 = pos0 + 16;
    for (int dj = 0; dj < 4; ++dj) {
      AO[aobase + (size_t)pos0 * 384 + dj * 16 + lr] = f2bf(o0[dj][j] * rv0[j]);
      AO[aobase + (size_t)pos1 * 384 + dj * 16 + lr] = f2bf(o1[dj][j] * rv1[j]);
    }
  }
}

// --------------------------- Proj GEMM (M=16384,N=384,K=384) ----------------
// Staging LDS reused post-loop as 128x64 fp32 transpose tile: f32x4 stores,
// 16 lanes = 256B contiguous destination segments.
__global__ __launch_bounds__(256) void k_proj(const u16* __restrict__ A,
                                              const u16* __restrict__ W,
                                              const float* __restrict__ bias,
                                              float* __restrict__ out) {
  __shared__ char smem[32768];  // [0,16K): As[2]; [16K,24K): Bs[2]; epilogue: T
  u16* const As = (u16*)smem;
  u16* const Bs = (u16*)(smem + 16384);
  const int tid = threadIdx.x, w = tid >> 6, l = tid & 63, lr = l & 15, lg = l >> 4;
  const int id = blockIdx.y * 6 + blockIdx.x;
  const int swz = (id & 7) * 96 + (id >> 3);
  const int tn = (swz % 6) * 64, tm = (swz / 6) * 128;
  const int r0 = tid >> 2, c8 = (tid & 3) * 8;

  f32x4 acc[2][4] = {};

  auto stage = [&](int buf, int kt) {
    const int k0 = kt * 32;
    char* da = (char*)(As + buf * 4096) + (w << 10);
    char* db = (char*)(Bs + buf * 2048) + (w << 10);
    gld16(A + (size_t)(tm + r0) * 384 + k0 + c8, da);
    gld16(A + (size_t)(tm + 64 + r0) * 384 + k0 + c8, da + 4096);
    gld16(W + (size_t)(tn + r0) * 384 + k0 + c8, db);
  };

  stage(0, 0);
  for (int kt = 0; kt < 12; ++kt) {
    __syncthreads();
    if (kt < 11) stage((kt + 1) & 1, kt + 1);
    const int buf = kt & 1;
    s16x8 af[2], bfr[4];
    for (int mi = 0; mi < 2; mi++)
      af[mi] = *(const s16x8*)&As[buf * 4096 + (w * 32 + mi * 16 + lr) * 32 + lg * 8];
    for (int ni = 0; ni < 4; ni++)
      bfr[ni] = *(const s16x8*)&Bs[buf * 2048 + (ni * 16 + lr) * 32 + lg * 8];
    for (int mi = 0; mi < 2; mi++)
      for (int ni = 0; ni < 4; ni++)
        acc[mi][ni] = MFMA16(af[mi], bfr[ni], acc[mi][ni]);
  }

  // ---- epilogue: LDS transpose (fp32, bias folded) + f32x4 stores ----
  __syncthreads();
  for (int mi = 0; mi < 2; mi++)
    for (int ni = 0; ni < 4; ni++) {
      const int n = ni * 16 + lr;
      const float bn = bias[tn + n];
      for (int j = 0; j < 4; j++) {
        const int m = w * 32 + mi * 16 + lg * 4 + j;
        *(float*)(smem + ((m * 256 + n * 4) ^ ((m & 7) << 4))) = acc[mi][ni][j] + bn;
      }
    }
  __syncthreads();
  const int rr = tid >> 4, cc = tid & 15;
  for (int s = 0; s < 8; ++s) {
    const int r = s * 16 + rr;
    f32x4 v = *(const f32x4*)(smem + ((r * 256 + cc * 16) ^ ((r & 7) << 4)));
    *(f32x4*)&out[(size_t)(tm + r) * 384 + tn + cc * 4] = v;
  }
}

// --------------------------- launch -----------------------------------------
extern "C" void kernel_launch(void* const* d_in, const int* in_sizes, int n_in,
                              void* d_out, int out_size, void* d_ws, size_t ws_size,
                              hipStream_t stream) {
  const float* x      = (const float*)d_in[0];  // [8,2048,384]
  const float* qkv_w  = (const float*)d_in[1];  // [1152,384]
  const float* proj_w = (const float*)d_in[2];  // [384,384]
  const float* proj_b = (const float*)d_in[3];  // [384]
  const float* temp   = (const float*)d_in[4];  // [6]
  float* out = (float*)d_out;

  u16* wqkvb  = (u16*)d_ws;            // 442368
  u16* wprojb = wqkvb + 442368;        // 147456
  u16* Qt     = wprojb + 147456;       // 6291456
  u16* Kb     = Qt + 6291456;          // 6291456
  u16* Vtb    = Kb + 6291456;          // 6291456
  u16* AOb    = Vtb + 6291456;         // 6291456

  k_cvt2<<<288, 256, 0, stream>>>(qkv_w, wqkvb, proj_w, wprojb);
  k_qkv<<<dim3(9, 128), 256, 0, stream>>>(x, wqkvb, temp, Qt, Kb, Vtb);
  k_attn<<<768, 256, 0, stream>>>(Qt, Kb, Vtb, AOb);
  k_proj<<<dim3(6, 128), 256, 0, stream>>>(AOb, wprojb, proj_b, out);
}

// Round 18
// 114.355 us; speedup vs baseline: 1.0067x; 1.0067x over previous
//
#include <hip/hip_runtime.h>

// ---------------------------------------------------------------------------
// LocalitySelfAttention: y = proj( attn(x@Wqkv^T) ) for B=8,N=2048,C=384,H=6
// All internal compute bf16 MFMA + fp32 accum. Output fp32.
// R18: k_cvt2 eliminated — weights converted inline in k_qkv/k_proj B-staging
// (reg-stage fp32 -> cvt_pk -> ds_write, the proven X path). One fewer
// dispatch + dependency gap. k_attn identical to R16; k_proj epilogue = R16.
// ---------------------------------------------------------------------------

using f32x4 = __attribute__((ext_vector_type(4))) float;
using s16x8 = __attribute__((ext_vector_type(8))) short;
using u16x4 = __attribute__((ext_vector_type(4))) unsigned short;
using u32x2 = __attribute__((ext_vector_type(2))) unsigned int;
using u32x4 = __attribute__((ext_vector_type(4))) unsigned int;
typedef unsigned short u16;
typedef unsigned int u32;

#define MFMA16(a, b, c) __builtin_amdgcn_mfma_f32_16x16x32_bf16(a, b, c, 0, 0, 0)
#define LOG2E 1.4426950408889634f
#define SQRTC 19.595917942265423f

__device__ __forceinline__ u16 f2bf(float f) {
  u32 u = __float_as_uint(f);
  u += 0x7fffu + ((u >> 16) & 1u);   // RNE
  return (u16)(u >> 16);
}

__device__ __forceinline__ u32 cvtpk(float lo, float hi) {
  u32 r;
  asm("v_cvt_pk_bf16_f32 %0, %1, %2" : "=v"(r) : "v"(lo), "v"(hi));
  return r;
}

__device__ __forceinline__ float fexp2(float x) {  // 2^x, single v_exp_f32
  float r;
  asm("v_exp_f32 %0, %1" : "=v"(r) : "v"(x));
  return r;
}

__device__ __forceinline__ void gld16(const void* g, void* l) {
  __builtin_amdgcn_global_load_lds((const __attribute__((address_space(1))) void*)g,
                                   (__attribute__((address_space(3))) void*)l, 16, 0, 0);
}

// --------------------------- QKV GEMM (M=16384,N=1152,K=384) ----------------
// A = x fp32, B = qkv_w fp32; both converted in the staging path.
// Staging LDS (32KB) reused post-loop as a 128x128 bf16 transpose tile.
__global__ __launch_bounds__(256) void k_qkv(const float* __restrict__ X,
                                             const float* __restrict__ Wf,
                                             const float* __restrict__ temp,
                                             u16* __restrict__ Qt,
                                             u16* __restrict__ Kb,
                                             u16* __restrict__ Vt) {
  __shared__ u16 smem[16384];   // [0,8192): As[2][4096]; [8192,16384): Bs[2][4096]
  const int tid = threadIdx.x, w = tid >> 6, l = tid & 63, lr = l & 15, lg = l >> 4;
  const int id = blockIdx.y * 9 + blockIdx.x;
  const int swz = (id & 7) * 144 + (id >> 3);
  const int tn = (swz % 9) * 128, tm = (swz / 9) * 128;
  const int wr = w >> 1, wc = w & 1;
  const int ar = tid >> 1, ac = (tid & 1) * 16;

  f32x4 acc[4][4] = {};
  f32x4 a4[4], b4[4];

  auto issueA = [&](int kt) {
    const float* xp = X + (size_t)(tm + ar) * 384 + kt * 32 + ac;
    a4[0] = *(const f32x4*)(xp);
    a4[1] = *(const f32x4*)(xp + 4);
    a4[2] = *(const f32x4*)(xp + 8);
    a4[3] = *(const f32x4*)(xp + 12);
  };
  auto issueB = [&](int kt) {
    const float* wp = Wf + (size_t)(tn + ar) * 384 + kt * 32 + ac;
    b4[0] = *(const f32x4*)(wp);
    b4[1] = *(const f32x4*)(wp + 4);
    b4[2] = *(const f32x4*)(wp + 8);
    b4[3] = *(const f32x4*)(wp + 12);
  };
  auto commitA = [&](int buf) {
    u32x4 h0, h1;
    h0[0] = cvtpk(a4[0][0], a4[0][1]); h0[1] = cvtpk(a4[0][2], a4[0][3]);
    h0[2] = cvtpk(a4[1][0], a4[1][1]); h0[3] = cvtpk(a4[1][2], a4[1][3]);
    h1[0] = cvtpk(a4[2][0], a4[2][1]); h1[1] = cvtpk(a4[2][2], a4[2][3]);
    h1[2] = cvtpk(a4[3][0], a4[3][1]); h1[3] = cvtpk(a4[3][2], a4[3][3]);
    *(u32x4*)&smem[buf * 4096 + ar * 32 + ac] = h0;
    *(u32x4*)&smem[buf * 4096 + ar * 32 + ac + 8] = h1;
  };
  auto commitB = [&](int buf) {
    u32x4 h0, h1;
    h0[0] = cvtpk(b4[0][0], b4[0][1]); h0[1] = cvtpk(b4[0][2], b4[0][3]);
    h0[2] = cvtpk(b4[1][0], b4[1][1]); h0[3] = cvtpk(b4[1][2], b4[1][3]);
    h1[0] = cvtpk(b4[2][0], b4[2][1]); h1[1] = cvtpk(b4[2][2], b4[2][3]);
    h1[2] = cvtpk(b4[3][0], b4[3][1]); h1[3] = cvtpk(b4[3][2], b4[3][3]);
    *(u32x4*)&smem[8192 + buf * 4096 + ar * 32 + ac] = h0;
    *(u32x4*)&smem[8192 + buf * 4096 + ar * 32 + ac + 8] = h1;
  };

  issueA(0); issueB(0); commitA(0); commitB(0);
  for (int kt = 0; kt < 12; ++kt) {
    __syncthreads();
    if (kt < 11) { issueA(kt + 1); issueB(kt + 1); }
    const int buf = kt & 1;
    s16x8 af[4], bfr[4];
    for (int mi = 0; mi < 4; mi++)
      af[mi] = *(const s16x8*)&smem[buf * 4096 + (wr * 64 + mi * 16 + lr) * 32 + lg * 8];
    for (int ni = 0; ni < 4; ni++)
      bfr[ni] = *(const s16x8*)&smem[8192 + buf * 4096 + (wc * 64 + ni * 16 + lr) * 32 + lg * 8];
    for (int mi = 0; mi < 4; mi++)
      for (int ni = 0; ni < 4; ni++)
        acc[mi][ni] = MFMA16(af[mi], bfr[ni], acc[mi][ni]);
    if (kt < 11) { commitA((kt + 1) & 1); commitB((kt + 1) & 1); }
  }

  // ------------------ epilogue: LDS transpose + coalesced stores ------------
  const int which = tn / 384;                 // block-uniform
  const int hbase = (tn - which * 384) >> 6;  // 0, 2, or 4
  const int bidx = tm >> 11;
  const int tml = tm & 2047;

  __syncthreads();   // all waves done reading staging LDS
  char* const T = (char*)smem;

  if (which == 1) {
    // K: T[m][n] rows of 256B; dest Kb[bh][pos][d] rows of 128B.
    for (int mi = 0; mi < 4; mi++)
      for (int ni = 0; ni < 4; ni++) {
        const int n = wc * 64 + ni * 16 + lr;
        for (int j = 0; j < 4; j++) {
          const int m = wr * 64 + mi * 16 + lg * 4 + j;
          *(u16*)(T + ((m * 256 + n * 2) ^ ((m & 7) << 4))) = f2bf(acc[mi][ni][j]);
        }
      }
    __syncthreads();
    for (int s = 0; s < 8; ++s) {
      const int rr = s * 16 + (tid >> 4), c = tid & 15;
      s16x8 v = *(const s16x8*)(T + ((rr * 256 + c * 16) ^ ((rr & 7) << 4)));
      const int hl = c >> 3, d0 = (c & 7) * 8;
      *(s16x8*)&Kb[((size_t)(bidx * 6 + hbase + hl) * 2048 + tml + rr) * 64 + d0] = v;
    }
  } else {
    // Q/V: T[n][m] transposed rows of 256B; dest [bh][d][pos] (pos-contig).
    const float mult = (which == 0) ? (LOG2E / (SQRTC * temp[hbase + wc])) : 1.0f;
    for (int mi = 0; mi < 4; mi++)
      for (int ni = 0; ni < 4; ni++) {
        const int n = wc * 64 + ni * 16 + lr;
        const int m0 = wr * 64 + mi * 16 + lg * 4;
        u16x4 vv;
        vv[0] = f2bf(acc[mi][ni][0] * mult); vv[1] = f2bf(acc[mi][ni][1] * mult);
        vv[2] = f2bf(acc[mi][ni][2] * mult); vv[3] = f2bf(acc[mi][ni][3] * mult);
        *(u16x4*)(T + ((n * 256 + m0 * 2) ^ ((n & 7) << 4))) = vv;
      }
    __syncthreads();
    u16* const dst = (which == 0) ? Qt : Vt;
    for (int s = 0; s < 8; ++s) {
      const int r = s * 16 + (tid >> 4), c = tid & 15;
      s16x8 v = *(const s16x8*)(T + ((r * 256 + c * 16) ^ ((r & 7) << 4)));
      const int hl = r >> 6, d = r & 63;
      *(s16x8*)&dst[((size_t)(bidx * 6 + hbase + hl) * 64 + d) * 2048 + tml + c * 8] = v;
    }
  }
}

// --------------------------- Flash attention (in-register P) ----------------
// grid = 48 bh * 16 q-tiles (XCD-swizzled). Block: 4 waves x 32 q-rows.
// K/V: reg-staged dbuf XOR-swizzled LDS. P packed in registers (sigma order);
// V read in sigma order via paired ds_read_b64. Row sums via ones-MFMA.
#define LDSOFF(row, c16) (((row) * 128 + (c16) * 16) ^ (((row) & 7) << 4))

__global__ __launch_bounds__(256, 3) void k_attn(const u16* __restrict__ Qt,
                                                 const u16* __restrict__ Kb,
                                                 const u16* __restrict__ Vt,
                                                 u16* __restrict__ AO) {
  __shared__ u16 Ks[2][64 * 64];
  __shared__ u16 Vs[2][64 * 64];
  const int tid = threadIdx.x, w = tid >> 6, l = tid & 63, lr = l & 15, lg = l >> 4;
  const int orig = blockIdx.x;
  const int rm = (orig & 7) * 96 + (orig >> 3);
  const int qt = rm & 15, bh = rm >> 4;
  const int h = bh % 6, b = bh / 6;
  const size_t base = (size_t)bh << 17;
  const int q0 = qt * 128 + w * 32;
  const int maskKt = q0 >> 6;
  const int qo = q0 & 63;

  s16x8 qf[2][2];
  for (int mi = 0; mi < 2; mi++)
    for (int ks = 0; ks < 2; ks++) {
      const u16* qp = Qt + base + (size_t)(ks * 32 + lg * 8) * 2048 + q0 + mi * 16 + lr;
      s16x8 q;
      for (int e = 0; e < 8; ++e) q[e] = (short)qp[(size_t)e * 2048];
      qf[mi][ks] = q;
    }

  s16x8 ones;
  for (int e = 0; e < 8; ++e) ones[e] = (short)0x3F80;  // bf16 1.0

  f32x4 o0[4] = {}, o1[4] = {};
  f32x4 os0 = {}, os1 = {};

  const int r0 = tid >> 3, c0 = tid & 7;
  const int c8 = c0 * 8;
  const int wo0 = LDSOFF(r0, c0), wo1 = LDSOFF(r0 + 32, c0);

  s16x8 ka0, ka1, va0, va1;
  auto issue = [&](int kt) {
    const u16* kp = Kb + base + (size_t)(kt * 64 + r0) * 64 + c8;
    ka0 = *(const s16x8*)kp;
    ka1 = *(const s16x8*)(kp + 32 * 64);
    const u16* vp = Vt + base + (size_t)r0 * 2048 + kt * 64 + c8;
    va0 = *(const s16x8*)vp;
    va1 = *(const s16x8*)(vp + 32 * 2048);
  };
  auto commit = [&](int buf) {
    char* kd = (char*)&Ks[buf][0];
    char* vd = (char*)&Vs[buf][0];
    *(s16x8*)(kd + wo0) = ka0; *(s16x8*)(kd + wo1) = ka1;
    *(s16x8*)(vd + wo0) = va0; *(s16x8*)(vd + wo1) = va1;
  };

  issue(0); commit(0);
  __syncthreads();

  const int lrs = (lr & 7) << 4;
  const int x0 = (lg * 16) ^ lrs;
  const int x1 = (64 + lg * 16) ^ lrs;
  const int vo0 = (lg * 8) ^ lrs;
  const int vo1 = (32 + lg * 8) ^ lrs;
  const int vo2 = (64 + lg * 8) ^ lrs;
  const int vo3 = (96 + lg * 8) ^ lrs;

  for (int kt = 0; kt < 32; ++kt) {
    const int cur = kt & 1;
    if (kt < 31) issue(kt + 1);

    f32x4 st0[4] = {}, st1[4] = {};
    const char* kbp = (const char*)&Ks[cur][0];
    __builtin_amdgcn_s_setprio(1);
    for (int ni = 0; ni < 4; ++ni) {
      const int rb = (ni * 16 + lr) * 128;
      const s16x8 kf0 = *(const s16x8*)(kbp + (rb + x0));
      const s16x8 kf1 = *(const s16x8*)(kbp + (rb + x1));
      st0[ni] = MFMA16(kf0, qf[0][0], st0[ni]);
      st0[ni] = MFMA16(kf1, qf[0][1], st0[ni]);
      st1[ni] = MFMA16(kf0, qf[1][0], st1[ni]);
      st1[ni] = MFMA16(kf1, qf[1][1], st1[ni]);
    }
    __builtin_amdgcn_s_setprio(0);

    if (kt == maskKt) {
      for (int ni = 0; ni < 4; ++ni)
        for (int j = 0; j < 4; ++j) {
          const int kvl = ni * 16 + lg * 4 + j;
          if (kvl == qo + lr)      st0[ni][j] = -1e30f;
          if (kvl == qo + 16 + lr) st1[ni][j] = -1e30f;
        }
    }

    const char* vbp = (const char*)&Vs[cur][0];
    s16x8 vfr[2][4];
    for (int dj = 0; dj < 4; ++dj) {
      const int rb = (dj * 16 + lr) * 128;
      u32x2 a = *(const u32x2*)(vbp + rb + vo0);
      u32x2 bq = *(const u32x2*)(vbp + rb + vo1);
      u32x2 c = *(const u32x2*)(vbp + rb + vo2);
      u32x2 d = *(const u32x2*)(vbp + rb + vo3);
      u32x4 t0; t0[0] = a[0]; t0[1] = a[1]; t0[2] = bq[0]; t0[3] = bq[1];
      u32x4 t1; t1[0] = c[0]; t1[1] = c[1]; t1[2] = d[0]; t1[3] = d[1];
      vfr[0][dj] = __builtin_bit_cast(s16x8, t0);
      vfr[1][dj] = __builtin_bit_cast(s16x8, t1);
    }

    {
      u32 pk[8];
      for (int ni = 0; ni < 4; ++ni) {
        pk[ni * 2]     = cvtpk(fexp2(st0[ni][0]), fexp2(st0[ni][1]));
        pk[ni * 2 + 1] = cvtpk(fexp2(st0[ni][2]), fexp2(st0[ni][3]));
      }
      u32x4 a0; a0[0] = pk[0]; a0[1] = pk[1]; a0[2] = pk[2]; a0[3] = pk[3];
      u32x4 a1; a1[0] = pk[4]; a1[1] = pk[5]; a1[2] = pk[6]; a1[3] = pk[7];
      const s16x8 pa0 = __builtin_bit_cast(s16x8, a0);
      const s16x8 pa1 = __builtin_bit_cast(s16x8, a1);
      __builtin_amdgcn_s_setprio(1);
      for (int dj = 0; dj < 4; ++dj) o0[dj] = MFMA16(pa0, vfr[0][dj], o0[dj]);
      os0 = MFMA16(pa0, ones, os0);
      for (int dj = 0; dj < 4; ++dj) o0[dj] = MFMA16(pa1, vfr[1][dj], o0[dj]);
      os0 = MFMA16(pa1, ones, os0);
      __builtin_amdgcn_s_setprio(0);
    }
    {
      u32 pk[8];
      for (int ni = 0; ni < 4; ++ni) {
        pk[ni * 2]     = cvtpk(fexp2(st1[ni][0]), fexp2(st1[ni][1]));
        pk[ni * 2 + 1] = cvtpk(fexp2(st1[ni][2]), fexp2(st1[ni][3]));
      }
      u32x4 a0; a0[0] = pk[0]; a0[1] = pk[1]; a0[2] = pk[2]; a0[3] = pk[3];
      u32x4 a1; a1[0] = pk[4]; a1[1] = pk[5]; a1[2] = pk[6]; a1[3] = pk[7];
      const s16x8 pa0 = __builtin_bit_cast(s16x8, a0);
      const s16x8 pa1 = __builtin_bit_cast(s16x8, a1);
      __builtin_amdgcn_s_setprio(1);
      for (int dj = 0; dj < 4; ++dj) o1[dj] = MFMA16(pa0, vfr[0][dj], o1[dj]);
      os1 = MFMA16(pa0, ones, os1);
      for (int dj = 0; dj < 4; ++dj) o1[dj] = MFMA16(pa1, vfr[1][dj], o1[dj]);
      os1 = MFMA16(pa1, ones, os1);
      __builtin_amdgcn_s_setprio(0);
    }

    if (kt < 31) commit(cur ^ 1);
    __syncthreads();
  }

  f32x4 rv0, rv1;
  for (int j = 0; j < 4; ++j) { rv0[j] = 1.0f / os0[j]; rv1[j] = 1.0f / os1[j]; }
  const size_t aobase = (size_t)b * 2048 * 384 + (size_t)h * 64;
  for (int j = 0; j < 4; ++j) {
    const int pos0 = q0 + lg * 4 + j;
    const int pos1 = pos0 + 16;
    for (int dj = 0; dj < 4; ++dj) {
      AO[aobase + (size_t)pos0 * 384 + dj * 16 + lr] = f2bf(o0[dj][j] * rv0[j]);
      AO[aobase + (size_t)pos1 * 384 + dj * 16 + lr] = f2bf(o1[dj][j] * rv1[j]);
    }
  }
}

// --------------------------- Proj GEMM (M=16384,N=384,K=384) ----------------
// B = proj_w fp32, converted inline in staging. Scalar epilogue (R16-best).
__global__ __launch_bounds__(256) void k_proj(const u16* __restrict__ A,
                                              const float* __restrict__ Wf,
                                              const float* __restrict__ bias,
                                              float* __restrict__ out) {
  __shared__ u16 As[2][128 * 32];
  __shared__ u16 Bs[2][64 * 32];
  const int tid = threadIdx.x, w = tid >> 6, l = tid & 63, lr = l & 15, lg = l >> 4;
  const int id = blockIdx.y * 6 + blockIdx.x;
  const int swz = (id & 7) * 96 + (id >> 3);
  const int tn = (swz % 6) * 64, tm = (swz / 6) * 128;
  const int r0 = tid >> 2, c8 = (tid & 3) * 8;

  f32x4 acc[2][4] = {};
  f32x4 b4[2];

  auto stageA = [&](int buf, int kt) {
    const int k0 = kt * 32;
    char* da = (char*)(&As[buf][0]) + (w << 10);
    gld16(A + (size_t)(tm + r0) * 384 + k0 + c8, da);
    gld16(A + (size_t)(tm + 64 + r0) * 384 + k0 + c8, da + 4096);
  };
  auto issueB = [&](int kt) {
    const float* wp = Wf + (size_t)(tn + (tid >> 2)) * 384 + kt * 32 + (tid & 3) * 8;
    b4[0] = *(const f32x4*)(wp);
    b4[1] = *(const f32x4*)(wp + 4);
  };
  auto commitB = [&](int buf) {
    u32x4 hh;
    hh[0] = cvtpk(b4[0][0], b4[0][1]); hh[1] = cvtpk(b4[0][2], b4[0][3]);
    hh[2] = cvtpk(b4[1][0], b4[1][1]); hh[3] = cvtpk(b4[1][2], b4[1][3]);
    *(u32x4*)&Bs[buf][(tid >> 2) * 32 + (tid & 3) * 8] = hh;
  };

  stageA(0, 0); issueB(0); commitB(0);
  for (int kt = 0; kt < 12; ++kt) {
    __syncthreads();
    if (kt < 11) { stageA((kt + 1) & 1, kt + 1); issueB(kt + 1); }
    const int buf = kt & 1;
    s16x8 af[2], bfr[4];
    for (int mi = 0; mi < 2; mi++)
      af[mi] = *(const s16x8*)&As[buf][(w * 32 + mi * 16 + lr) * 32 + lg * 8];
    for (int ni = 0; ni < 4; ni++)
      bfr[ni] = *(const s16x8*)&Bs[buf][(ni * 16 + lr) * 32 + lg * 8];
    for (int mi = 0; mi < 2; mi++)
      for (int ni = 0; ni < 4; ni++)
        acc[mi][ni] = MFMA16(af[mi], bfr[ni], acc[mi][ni]);
    if (kt < 11) commitB((kt + 1) & 1);
  }

  for (int mi = 0; mi < 2; mi++)
    for (int ni = 0; ni < 4; ni++) {
      const int n = tn + ni * 16 + lr;
      const float bn = bias[n];
      for (int j = 0; j < 4; j++) {
        const int m = tm + w * 32 + mi * 16 + lg * 4 + j;
        out[(size_t)m * 384 + n] = acc[mi][ni][j] + bn;
      }
    }
}

// --------------------------- launch -----------------------------------------
extern "C" void kernel_launch(void* const* d_in, const int* in_sizes, int n_in,
                              void* d_out, int out_size, void* d_ws, size_t ws_size,
                              hipStream_t stream) {
  const float* x      = (const float*)d_in[0];  // [8,2048,384]
  const float* qkv_w  = (const float*)d_in[1];  // [1152,384]
  const float* proj_w = (const float*)d_in[2];  // [384,384]
  const float* proj_b = (const float*)d_in[3];  // [384]
  const float* temp   = (const float*)d_in[4];  // [6]
  float* out = (float*)d_out;

  u16* Qt  = (u16*)d_ws;         // 6291456
  u16* Kb  = Qt + 6291456;       // 6291456
  u16* Vtb = Kb + 6291456;       // 6291456
  u16* AOb = Vtb + 6291456;      // 6291456

  k_qkv<<<dim3(9, 128), 256, 0, stream>>>(x, qkv_w, temp, Qt, Kb, Vtb);
  k_attn<<<768, 256, 0, stream>>>(Qt, Kb, Vtb, AOb);
  k_proj<<<dim3(6, 128), 256, 0, stream>>>(AOb, proj_w, proj_b, out);
}